// Round 5
// baseline (146.907 us; speedup 1.0000x reference)
//
#include <hip/hip_runtime.h>

#define E_TOTAL 262144
#define TPB 256
#define NBLK 512
#define EPT 8
#define GPB (TPB/4)          // pairs per block per k-iter = 64
#define W0S 516              // per-type float stride for sW0 (512 + 4 pad)
#define W1S 260              // per-type float stride for sW1 (256 + 4 pad)

__device__ __forceinline__ float silu_f(float x) {
    return x / (1.0f + __expf(-x));
}

// 4 lanes cooperate on one pair; lane (tid&3) owns channels h = lane*8 .. lane*8+7.
// PHASE 0: BN1 stats of out1; last block folds mean/var/gamma/beta -> ab1.
// PHASE 1: recompute out1, BN1+SiLU, second matvec; BN2 stats; last block -> ab2.
// PHASE 2: full recompute, BN2+SiLU, write output.
template<int PHASE>
__global__ __launch_bounds__(TPB, 2)
void nep_main(const int* __restrict__ ij,
              const float* __restrict__ fn,
              const float* __restrict__ W0g,
              const float* __restrict__ W1g,
              const float* __restrict__ ab1,
              const float* __restrict__ ab2,
              float* __restrict__ partial,
              float* __restrict__ ab_out,
              const float* __restrict__ gamma,
              const float* __restrict__ beta,
              const int* __restrict__ norm,
              unsigned int* __restrict__ counter,
              float* __restrict__ out)
{
    __shared__ __align__(16) float sW0[16 * W0S];
    __shared__ __align__(16) float sW1[(PHASE >= 1) ? 16 * W1S : 4];
    __shared__ float sAB1[64];
    __shared__ float sAB2[16];
    __shared__ float sredS[4][32];
    __shared__ float sredQ[4][32];
    __shared__ float fsum[TPB];   // finalize scratch: JW*NS == TPB for both phases
    __shared__ float fsq [TPB];
    __shared__ unsigned int slast;

    const int tid = threadIdx.x;
    const int bid = blockIdx.x;
    const int lane4 = tid & 3;
    const int grp = tid >> 2;

    // Stage W0 -> LDS with XOR block swizzle: row h block j stored at j ^ ((h>>3)&3).
    {
        const float4* W04 = (const float4*)W0g;
        #pragma unroll
        for (int i = 0; i < 8; i++) {
            int g4 = tid + i * TPB;              // 0..2047
            float4 v = W04[g4];
            int t = g4 >> 7;
            int h = (g4 >> 2) & 31;
            int j = g4 & 3;
            int js = j ^ ((h >> 3) & 3);
            *(float4*)&sW0[t * W0S + h * 16 + js * 4] = v;
        }
    }
    if constexpr (PHASE >= 1) {
        // W1 global layout [t][n][h] -> LDS [t][h*8 + n]
        const float4* W14 = (const float4*)W1g;
        #pragma unroll
        for (int i = 0; i < 4; i++) {
            int g4 = tid + i * TPB;              // 0..1023
            float4 v = W14[g4];
            int g = g4 * 4;
            int t = g >> 8;
            int n = (g >> 5) & 7;
            int h0 = g & 31;                     // multiple of 4
            sW1[t * W1S + (h0 + 0) * 8 + n] = v.x;
            sW1[t * W1S + (h0 + 1) * 8 + n] = v.y;
            sW1[t * W1S + (h0 + 2) * 8 + n] = v.z;
            sW1[t * W1S + (h0 + 3) * 8 + n] = v.w;
        }
        if (tid < 64) sAB1[tid] = ab1[tid];
    }
    if constexpr (PHASE == 2) {
        if (tid < 16) sAB2[tid] = ab2[tid];
    }
    __syncthreads();

    float s1[8], s2[8];
    #pragma unroll
    for (int c = 0; c < 8; c++) { s1[c] = 0.f; s2[c] = 0.f; }

    // Software-pipelined pair loop: prefetch next iter's ij/fn during compute.
    const int base = bid * (GPB * EPT) + grp;
    int t_nx = ij[base];
    const float4* f4 = (const float4*)(fn + (size_t)base * 16);
    float4 fa_nx = f4[0], fb_nx = f4[1], fc_nx = f4[2], fd_nx = f4[3];

    #pragma unroll 1
    for (int k = 0; k < EPT; k++) {
        const int p = base + k * GPB;
        const int t = t_nx;
        float4 fa = fa_nx, fb = fb_nx, fc = fc_nx, fd = fd_nx;
        if (k + 1 < EPT) {
            const int pn = p + GPB;
            t_nx = ij[pn];
            const float4* fn4 = (const float4*)(fn + (size_t)pn * 16);
            fa_nx = fn4[0]; fb_nx = fn4[1]; fc_nx = fn4[2]; fd_nx = fn4[3];
        }
        const float* w0t = &sW0[t * W0S];

        float o2[8];
        if constexpr (PHASE >= 1) {
            #pragma unroll
            for (int n = 0; n < 8; n++) o2[n] = 0.f;
        }

        #pragma unroll
        for (int hh = 0; hh < 8; hh++) {
            const int h = lane4 * 8 + hh;
            const float* wr = w0t + h * 16;
            const int x = lane4;                 // == (h>>3)&3
            float4 wA = *(const float4*)(wr + ((0 ^ x) << 2));
            float4 wB = *(const float4*)(wr + ((1 ^ x) << 2));
            float4 wC = *(const float4*)(wr + ((2 ^ x) << 2));
            float4 wD = *(const float4*)(wr + ((3 ^ x) << 2));
            float d = wA.x * fa.x + wA.y * fa.y + wA.z * fa.z + wA.w * fa.w
                    + wB.x * fb.x + wB.y * fb.y + wB.z * fb.z + wB.w * fb.w
                    + wC.x * fc.x + wC.y * fc.y + wC.z * fc.z + wC.w * fc.w
                    + wD.x * fd.x + wD.y * fd.y + wD.z * fd.z + wD.w * fd.w;
            if constexpr (PHASE == 0) {
                s1[hh] += d;
                s2[hh] += d * d;
            } else {
                float xv = sAB1[h] * d + sAB1[32 + h];
                float a = silu_f(xv);
                const float* wn = &sW1[t * W1S + h * 8];
                float4 pA = *(const float4*)(wn);
                float4 pB = *(const float4*)(wn + 4);
                o2[0] += pA.x * a; o2[1] += pA.y * a; o2[2] += pA.z * a; o2[3] += pA.w * a;
                o2[4] += pB.x * a; o2[5] += pB.y * a; o2[6] += pB.z * a; o2[7] += pB.w * a;
            }
        }

        if constexpr (PHASE >= 1) {
            #pragma unroll
            for (int n = 0; n < 8; n++) {
                o2[n] += __shfl_xor(o2[n], 1, 64);
                o2[n] += __shfl_xor(o2[n], 2, 64);
            }
        }
        if constexpr (PHASE == 1) {
            if (lane4 == 0) {
                #pragma unroll
                for (int n = 0; n < 8; n++) { s1[n] += o2[n]; s2[n] += o2[n] * o2[n]; }
            }
        }
        if constexpr (PHASE == 2) {
            float r0 = silu_f(sAB2[0] * o2[0] + sAB2[8 + 0]);
            float r1 = silu_f(sAB2[1] * o2[1] + sAB2[8 + 1]);
            float r2 = silu_f(sAB2[2] * o2[2] + sAB2[8 + 2]);
            float r3 = silu_f(sAB2[3] * o2[3] + sAB2[8 + 3]);
            float r4 = silu_f(sAB2[4] * o2[4] + sAB2[8 + 4]);
            float r5 = silu_f(sAB2[5] * o2[5] + sAB2[8 + 5]);
            float r6 = silu_f(sAB2[6] * o2[6] + sAB2[8 + 6]);
            float r7 = silu_f(sAB2[7] * o2[7] + sAB2[8 + 7]);
            float e0 = (lane4 == 0) ? r0 : (lane4 == 1) ? r2 : (lane4 == 2) ? r4 : r6;
            float e1 = (lane4 == 0) ? r1 : (lane4 == 1) ? r3 : (lane4 == 2) ? r5 : r7;
            *(float2*)(out + (size_t)p * 8 + lane4 * 2) = make_float2(e0, e1);
        }
    }

    if constexpr (PHASE == 0) {
        #pragma unroll
        for (int c = 0; c < 8; c++) {
            float v1 = s1[c], v2 = s2[c];
            v1 += __shfl_xor(v1, 4, 64);  v2 += __shfl_xor(v2, 4, 64);
            v1 += __shfl_xor(v1, 8, 64);  v2 += __shfl_xor(v2, 8, 64);
            v1 += __shfl_xor(v1, 16, 64); v2 += __shfl_xor(v2, 16, 64);
            v1 += __shfl_xor(v1, 32, 64); v2 += __shfl_xor(v2, 32, 64);
            s1[c] = v1; s2[c] = v2;
        }
        const int wid = tid >> 6;
        if ((tid & 63) < 4) {
            #pragma unroll
            for (int c = 0; c < 8; c++) {
                sredS[wid][lane4 * 8 + c] = s1[c];
                sredQ[wid][lane4 * 8 + c] = s2[c];
            }
        }
        __syncthreads();
        if (tid < 32) {
            float a = sredS[0][tid] + sredS[1][tid] + sredS[2][tid] + sredS[3][tid];
            float b = sredQ[0][tid] + sredQ[1][tid] + sredQ[2][tid] + sredQ[3][tid];
            partial[bid * 64 + tid]      = a;
            partial[bid * 64 + 32 + tid] = b;
        }
    }
    if constexpr (PHASE == 1) {
        #pragma unroll
        for (int c = 0; c < 8; c++) {
            float v1 = s1[c], v2 = s2[c];
            v1 += __shfl_xor(v1, 4, 64);  v2 += __shfl_xor(v2, 4, 64);
            v1 += __shfl_xor(v1, 8, 64);  v2 += __shfl_xor(v2, 8, 64);
            v1 += __shfl_xor(v1, 16, 64); v2 += __shfl_xor(v2, 16, 64);
            v1 += __shfl_xor(v1, 32, 64); v2 += __shfl_xor(v2, 32, 64);
            s1[c] = v1; s2[c] = v2;
        }
        const int wid = tid >> 6;
        if ((tid & 63) == 0) {
            #pragma unroll
            for (int n = 0; n < 8; n++) { sredS[wid][n] = s1[n]; sredQ[wid][n] = s2[n]; }
        }
        __syncthreads();
        if (tid < 8) {
            float a = sredS[0][tid] + sredS[1][tid] + sredS[2][tid] + sredS[3][tid];
            float b = sredQ[0][tid] + sredQ[1][tid] + sredQ[2][tid] + sredQ[3][tid];
            partial[bid * 16 + tid]     = a;
            partial[bid * 16 + 8 + tid] = b;
        }
    }

    // ---- last-block deterministic finalize: fold BN stats into affine ab_out ----
    if constexpr (PHASE <= 1) {
        __threadfence();                              // release: partial writes visible
        if (tid == 0) slast = atomicAdd(counter, 1u);
        __syncthreads();
        if (slast == NBLK - 1) {
            __threadfence();                          // acquire: invalidate caches before
                                                      // reading other XCDs' partials
            constexpr int NS = (PHASE == 0) ? 32 : 8;
            constexpr int JW = TPB / NS;
            const int c = tid & (NS - 1);
            const int j = tid / NS;
            float s = 0.f, q = 0.f;
            for (int blk = j; blk < NBLK; blk += JW) {
                s += partial[blk * (2 * NS) + c];
                q += partial[blk * (2 * NS) + NS + c];
            }
            fsum[j * NS + c] = s; fsq[j * NS + c] = q;
            __syncthreads();
            if (tid < NS) {
                float st = 0.f, qt = 0.f;
                #pragma unroll
                for (int jj = 0; jj < JW; jj++) { st += fsum[jj * NS + c]; qt += fsq[jj * NS + c]; }
                const float invE = 1.0f / (float)E_TOTAL;
                float mean = st * invE;
                float var  = qt * invE - mean * mean;
                float inv  = rsqrtf(var + 1e-5f);
                float a, b;
                if (*norm) {
                    a = gamma[c] * inv;
                    b = beta[c] - mean * a;
                } else {
                    a = 1.f; b = 0.f;
                }
                ab_out[c] = a;
                ab_out[NS + c] = b;
            }
        }
    }
}

extern "C" void kernel_launch(void* const* d_in, const int* in_sizes, int n_in,
                              void* d_out, int out_size, void* d_ws, size_t ws_size,
                              hipStream_t stream)
{
    const int*   ij   = (const int*)d_in[0];
    const float* fn   = (const float*)d_in[1];
    const float* W0   = (const float*)d_in[2];
    const float* W1   = (const float*)d_in[3];
    const float* g1   = (const float*)d_in[4];
    const float* b1   = (const float*)d_in[5];
    const float* g2   = (const float*)d_in[6];
    const float* b2   = (const float*)d_in[7];
    const int*   norm = (const int*)d_in[8];
    float* out = (float*)d_out;

    float* p1  = (float*)d_ws;                  // NBLK * 64 floats
    float* p2  = p1 + NBLK * 64;                // NBLK * 16 floats
    float* ab1 = p2 + NBLK * 16;                // 64 floats
    float* ab2 = ab1 + 64;                      // 16 floats
    unsigned int* ctr = (unsigned int*)(ab2 + 16);  // 2 uints

    hipMemsetAsync(ctr, 0, 2 * sizeof(unsigned int), stream);

    nep_main<0><<<NBLK, TPB, 0, stream>>>(ij, fn, W0, W1, nullptr, nullptr,
                                          p1, ab1, g1, b1, norm, ctr, nullptr);
    nep_main<1><<<NBLK, TPB, 0, stream>>>(ij, fn, W0, W1, ab1, nullptr,
                                          p2, ab2, g2, b2, norm, ctr + 1, nullptr);
    nep_main<2><<<NBLK, TPB, 0, stream>>>(ij, fn, W0, W1, ab1, ab2,
                                          nullptr, nullptr, nullptr, nullptr, nullptr, nullptr, out);
}